// Round 3
// baseline (338.152 us; speedup 1.0000x reference)
//
#include <hip/hip_runtime.h>

// Problem constants (B,C,S,E) = (8,16,512,256), fp32 in/out.
constexpr int BATCH = 8;
constexpr int CYC   = 16;
constexpr int SEQ   = 512;
constexpr int EMB   = 256;

typedef __attribute__((ext_vector_type(8))) short bf16x8;
typedef __attribute__((ext_vector_type(4))) float f32x4;

__device__ __forceinline__ unsigned short f2bf(float x) {
    unsigned int u = __float_as_uint(x);
    u += 0x7fffu + ((u >> 16) & 1u);   // RNE
    return (unsigned short)(u >> 16);
}
__device__ __forceinline__ unsigned int pk2(float lo, float hi) {
    return (unsigned int)f2bf(lo) | ((unsigned int)f2bf(hi) << 16);
}
__device__ __forceinline__ f32x4 mfma16(bf16x8 a, bf16x8 b, f32x4 c) {
    return __builtin_amdgcn_mfma_f32_16x16x32_bf16(a, b, c, 0, 0, 0);
}
// async global->LDS, 16B/lane; LDS dst = wave-uniform base + lane*16
__device__ __forceinline__ void gll16(const void* g, void* l) {
    __builtin_amdgcn_global_load_lds(
        (const __attribute__((address_space(1))) void*)g,
        (__attribute__((address_space(3))) void*)l, 16, 0, 0);
}

// ---------------------------------------------------------------------------
// Kernel 0: W[c][e][f] fp32 -> Wt[c][f][e] bf16.  grid (4,4,C), block 256.
// EXACT R0 version (3 launches) — reverted as part of the accounting bisect.
// ---------------------------------------------------------------------------
__global__ __launch_bounds__(256) void wt_kernel(const float* __restrict__ W,
                                                 unsigned short* __restrict__ Wt) {
    __shared__ float tile[64][65];
    const int c  = blockIdx.z;
    const int e0 = blockIdx.x * 64;
    const int f0 = blockIdx.y * 64;
    const float* Wc = W + (size_t)c * EMB * EMB;
    unsigned short* Wtc = Wt + (size_t)c * EMB * EMB;
    const int t = threadIdx.x;
    {
        const int er = t >> 4;
        const int fc = (t & 15) * 4;
        for (int i = 0; i < 4; ++i) {
            const float4 v = *(const float4*)(Wc + (size_t)(e0 + er + i * 16) * EMB + f0 + fc);
            tile[er + i * 16][fc + 0] = v.x;
            tile[er + i * 16][fc + 1] = v.y;
            tile[er + i * 16][fc + 2] = v.z;
            tile[er + i * 16][fc + 3] = v.w;
        }
    }
    __syncthreads();
    {
        const int fr = t >> 4;
        const int ec = (t & 15) * 4;
        for (int i = 0; i < 4; ++i) {
            const int f = fr + i * 16;
            ushort4 o;
            o.x = f2bf(tile[ec + 0][f]);
            o.y = f2bf(tile[ec + 1][f]);
            o.z = f2bf(tile[ec + 2][f]);
            o.w = f2bf(tile[ec + 3][f]);
            *(ushort4*)(Wtc + (size_t)(f0 + f) * EMB + e0 + ec) = o;
        }
    }
}

// ---------------------------------------------------------------------------
// Kernel 1 (v3): merged q/k/v projection.  Y = relu(X_f32 @ W + bias) * scale.
// grid (128, 8, 3), block 256.  Tile 64(m) x 256(n), BK=32, 8 K-steps.
// Changes vs v2 (the ONLY kernel changed this round):
//   * A staged as bf16 (pack ONCE at stage, not 4x redundantly per wave at
//     frag-read): -75% pack VALU, A LDS 16KB->4KB per buffer.
//   * LDS 49152 -> 40960 B  =>  4 blocks/CU (16 waves) instead of 3.
//   * counted-vmcnt pipeline kept; A-reg loads pinned BEFORE B glls
//     (sched_barrier) so vmcnt counts stay exact:
//       top of step k:  vmcnt(4)  -> A(k) regs ready   (B(k) still flying)
//       after issuing A(k+1)x2 + B(k+1)x4:  vmcnt(6) -> B(k) landed
//     never drained to 0 inside the loop.
// A frag reads [(i*16+ln)*32 + quad*8] cover a contiguous 1KB region with 64
// distinct 16B chunks -> bank-conflict-free, no swizzle needed.
// ---------------------------------------------------------------------------
__global__ __launch_bounds__(256, 4) void proj_kernel(
    const float* __restrict__ Xq, const float* __restrict__ Xk,
    const float* __restrict__ Xv,
    const unsigned short* __restrict__ Wq, const unsigned short* __restrict__ Wk,
    const unsigned short* __restrict__ Wv,
    const float* __restrict__ Bq, const float* __restrict__ Bk,
    const float* __restrict__ Bv,
    unsigned short* __restrict__ Yq, unsigned short* __restrict__ Yk,
    unsigned short* __restrict__ Yv)
{
    __shared__ unsigned short As[2][64 * 32];    //  8 KiB total, bf16
    __shared__ unsigned short Bs[2][256 * 32];   // 32 KiB total, bf16, chunk-swizzled

    const int z = blockIdx.z;
    const float* X = z == 0 ? Xq : z == 1 ? Xk : Xv;
    const unsigned short* Wt = z == 0 ? Wq : z == 1 ? Wk : Wv;
    const float* bias = z == 0 ? Bq : z == 1 ? Bk : Bv;
    unsigned short* Y = z == 0 ? Yq : z == 1 ? Yk : Yv;
    const float scale = z == 0 ? 0.0625f : 1.0f;   // E^-0.5 folded into q

    const int bc = blockIdx.x;
    const int c  = bc & (CYC - 1);
    const int m0 = blockIdx.y * 64;
    const float* Xb = X + (size_t)bc * SEQ * EMB;
    const unsigned short* Wc = Wt + (size_t)c * EMB * EMB;
    const float* bb = bias + (size_t)c * EMB;
    unsigned short* Yb = Y + (size_t)bc * SEQ * EMB;

    const int tid  = threadIdx.x;
    const int lane = tid & 63, w = tid >> 6;
    const int ln   = lane & 15, quad = lane >> 4;
    const int wu   = __builtin_amdgcn_readfirstlane(w);

    // A reg-stage: thread t owns row ar = t>>2, 8 floats at col (t&3)*8.
    const int ar = tid >> 2, ac = (tid & 3) * 8;
    // B gll: per call 16 rows x 64B; source chunk ^ ((row-in-group)>>1 & 3).
    const int brow = lane >> 2;
    const int gch  = (lane & 3) ^ ((lane >> 3) & 3);
    const int bslot = quad ^ ((ln >> 1) & 3);  // B frag un-swizzle

    f32x4 acc[4][4];
    for (int i = 0; i < 4; ++i)
        for (int j = 0; j < 4; ++j) acc[i][j] = (f32x4){0.f, 0.f, 0.f, 0.f};

    const float* aptr = Xb + (size_t)(m0 + ar) * EMB + ac;
    float4 a0, a1;                             // A(k+1) in-flight regs

    auto aload = [&](int kk) {                 // 2 global_load_dwordx4
        const float* p = aptr + kk * 32;
        a0 = *(const float4*)p;
        a1 = *(const float4*)(p + 4);
    };
    auto bstage = [&](int kk, int b) {         // 4 global_load_lds_dwordx4
        const int k0 = kk * 32;
#pragma unroll
        for (int j = 0; j < 4; ++j) {
            const int r0 = wu * 64 + j * 16;
            gll16(Wc + (size_t)(r0 + brow) * EMB + k0 + gch * 8,
                  &Bs[b][r0 * 32]);
        }
    };

    aload(0);
    __builtin_amdgcn_sched_barrier(0);         // pin A-issue before B-issue
    bstage(0, 0);

#pragma unroll
    for (int kk = 0; kk < 8; ++kk) {
        const int cur = kk & 1;
        // A(kk) regs ready (the 2 oldest vmem ops); B(kk) may still fly.
        asm volatile("s_waitcnt vmcnt(4)" ::: "memory");
        {   // pack fp32->bf16 once, one ds_write_b128 per thread
            int4 pk;
            pk.x = pk2(a0.x, a0.y); pk.y = pk2(a0.z, a0.w);
            pk.z = pk2(a1.x, a1.y); pk.w = pk2(a1.z, a1.w);
            *(int4*)&As[cur][ar * 32 + ac] = pk;
        }
        if (kk < 7) {
            aload(kk + 1);
            __builtin_amdgcn_sched_barrier(0); // keep vmcnt order A then B
            bstage(kk + 1, cur ^ 1);
            asm volatile("s_waitcnt vmcnt(6)" ::: "memory");   // B(kk) landed
        } else {
            asm volatile("s_waitcnt vmcnt(0)" ::: "memory");
        }
        asm volatile("s_waitcnt lgkmcnt(0)" ::: "memory");     // A writes visible
        __builtin_amdgcn_s_barrier();
        __builtin_amdgcn_sched_barrier(0);

        bf16x8 af[4], bfv[4];
#pragma unroll
        for (int i = 0; i < 4; ++i)
            af[i] = *(const bf16x8*)&As[cur][(i * 16 + ln) * 32 + quad * 8];
#pragma unroll
        for (int j = 0; j < 4; ++j)
            bfv[j] = *(const bf16x8*)&Bs[cur][(w * 64 + j * 16 + ln) * 32 + bslot * 8];
#pragma unroll
        for (int i = 0; i < 4; ++i)
#pragma unroll
            for (int j = 0; j < 4; ++j)
                acc[i][j] = mfma16(af[i], bfv[j], acc[i][j]);

        __builtin_amdgcn_sched_barrier(0);
        asm volatile("s_waitcnt lgkmcnt(0)" ::: "memory");
        __builtin_amdgcn_s_barrier();
    }

    // Epilogue.  C/D layout: col = lane&15, row = quad*4 + reg  [m89-verified]
    float bvj[4];
#pragma unroll
    for (int j = 0; j < 4; ++j) bvj[j] = bb[w * 64 + j * 16 + ln];

    if (z != 2) {
        // per-wave LDS transpose tile [16][72] -> coalesced 16B row stores
        // (scratch carved from Bs: 4 x 2304B = 9216B <= 32KB, loop is done)
        unsigned short* ep = &Bs[0][0] + w * 1152;
        for (int i = 0; i < 4; ++i) {
            for (int j = 0; j < 4; ++j)
                for (int r = 0; r < 4; ++r)
                    ep[(quad * 4 + r) * 72 + j * 16 + ln] =
                        f2bf(fmaxf(acc[i][j][r] + bvj[j], 0.f) * scale);
            __syncthreads();
            for (int h = 0; h < 2; ++h) {
                const int cid = lane + h * 64;       // [16 rows][8 chunks]
                const int row = cid >> 3, ch = cid & 7;
                *(bf16x8*)&Yb[(size_t)(m0 + i * 16 + row) * EMB + w * 64 + ch * 8] =
                    *(const bf16x8*)&ep[row * 72 + ch * 8];
            }
            __syncthreads();
        }
    } else {
        // V path: store transposed  Yb[f][t]
        for (int j = 0; j < 4; ++j) {
            const int fg = w * 64 + j * 16 + ln;
            for (int i = 0; i < 4; ++i) {
                const int mb = m0 + i * 16 + quad * 4;
                ushort4 u;
                u.x = f2bf(fmaxf(acc[i][j][0] + bvj[j], 0.f) * scale);
                u.y = f2bf(fmaxf(acc[i][j][1] + bvj[j], 0.f) * scale);
                u.z = f2bf(fmaxf(acc[i][j][2] + bvj[j], 0.f) * scale);
                u.w = f2bf(fmaxf(acc[i][j][3] + bvj[j], 0.f) * scale);
                *(ushort4*)&Yb[(size_t)fg * SEQ + mb] = u;
            }
        }
    }
}

// ---------------------------------------------------------------------------
// Kernel 2: attention per (b,c) — EXACT R0 version (85 us, accounting-clean).
// Reverted as part of the bisect: only proj changes this round.
// ---------------------------------------------------------------------------
__global__ __launch_bounds__(256) void attn_kernel(
    const unsigned short* __restrict__ Qp, const unsigned short* __restrict__ Kp,
    const unsigned short* __restrict__ Vt, float* __restrict__ Out)
{
    __shared__ unsigned short Ks[32][264];  // [t][e]
    __shared__ unsigned short Vs[256][40];  // [e][t]
    __shared__ unsigned short Ps[64][40];   // [m][t]
    const int bc = blockIdx.x;
    const int qt = blockIdx.y;
    const unsigned short* Qb = Qp + (size_t)bc * SEQ * EMB;
    const unsigned short* Kb = Kp + (size_t)bc * SEQ * EMB;
    const unsigned short* Vb = Vt + (size_t)bc * SEQ * EMB;  // [e][t]
    float* Ob = Out + (size_t)bc * SEQ * EMB;

    const int tid  = threadIdx.x;
    const int lane = tid & 63, w = tid >> 6;
    const int ln   = lane & 15, quad = lane >> 4;

    bf16x8 qf[8];
    const int qrow = qt * 64 + w * 16 + ln;
    for (int ke = 0; ke < 8; ++ke)
        qf[ke] = *(const bf16x8*)(Qb + (size_t)qrow * EMB + ke * 32 + quad * 8);

    f32x4 of[16];
    for (int n = 0; n < 16; ++n) of[n] = (f32x4){0.f, 0.f, 0.f, 0.f};
    float lsum[4] = {0.f, 0.f, 0.f, 0.f};

    for (int tt = 0; tt < 16; ++tt) {
        const int t0 = tt * 32;
        for (int i = 0; i < 4; ++i) {       // stage K chunk: 32 x 256 bf16
            const int idx = tid + i * 256;
            const int r = idx >> 5, c8 = (idx & 31) * 8;
            *(bf16x8*)&Ks[r][c8] = *(const bf16x8*)(Kb + (size_t)(t0 + r) * EMB + c8);
        }
        for (int i = 0; i < 4; ++i) {       // stage V chunk: 256 x 32 bf16
            const int idx = tid + i * 256;
            const int e = idx >> 2, c8 = (idx & 3) * 8;
            *(bf16x8*)&Vs[e][c8] = *(const bf16x8*)(Vb + (size_t)e * SEQ + t0 + c8);
        }
        __syncthreads();

        // QK^T
        f32x4 sf0 = (f32x4){0.f,0.f,0.f,0.f}, sf1 = (f32x4){0.f,0.f,0.f,0.f};
        for (int ke = 0; ke < 8; ++ke) {
            bf16x8 b0 = *(const bf16x8*)&Ks[ln][ke * 32 + quad * 8];
            bf16x8 b1 = *(const bf16x8*)&Ks[16 + ln][ke * 32 + quad * 8];
            sf0 = mfma16(qf[ke], b0, sf0);
            sf1 = mfma16(qf[ke], b1, sf1);
        }

        float p0[4], p1[4];
        for (int r = 0; r < 4; ++r) {
            p0[r] = __expf(sf0[r]);
            p1[r] = __expf(sf1[r]);
            lsum[r] += p0[r] + p1[r];
        }
        for (int r = 0; r < 4; ++r) {
            Ps[w * 16 + quad * 4 + r][ln]      = f2bf(p0[r]);
            Ps[w * 16 + quad * 4 + r][16 + ln] = f2bf(p1[r]);
        }
        __syncthreads();

        // PV: O[m][e] += P[m][t] V[t][e]
        bf16x8 af = *(const bf16x8*)&Ps[w * 16 + ln][quad * 8];
        for (int n = 0; n < 16; ++n) {
            bf16x8 bv = *(const bf16x8*)&Vs[n * 16 + ln][quad * 8];
            of[n] = mfma16(af, bv, of[n]);
        }
        __syncthreads();
    }

    for (int off = 1; off < 16; off <<= 1)
        for (int r = 0; r < 4; ++r)
            lsum[r] += __shfl_xor(lsum[r], off, 64);
    float inv[4];
    for (int r = 0; r < 4; ++r) inv[r] = 1.0f / lsum[r];
    const int mbase = qt * 64 + w * 16 + quad * 4;
    for (int n = 0; n < 16; ++n)
        for (int r = 0; r < 4; ++r)
            Ob[(size_t)(mbase + r) * EMB + n * 16 + ln] = of[n][r] * inv[r];
}

// ---------------------------------------------------------------------------
extern "C" void kernel_launch(void* const* d_in, const int* in_sizes, int n_in,
                              void* d_out, int out_size, void* d_ws, size_t ws_size,
                              hipStream_t stream) {
    const float* query = (const float*)d_in[0];
    const float* key_  = (const float*)d_in[1];
    const float* value = (const float*)d_in[2];
    const float* wq = (const float*)d_in[3];
    const float* wk = (const float*)d_in[4];
    const float* wv = (const float*)d_in[5];
    const float* bq = (const float*)d_in[6];
    const float* bk = (const float*)d_in[7];
    const float* bv = (const float*)d_in[8];
    float* out = (float*)d_out;

    // Workspace: Wt q/k/v bf16 (2 MiB ea) | Qp, Kp, Vtp bf16 (32 MiB ea)
    char* ws = (char*)d_ws;
    const size_t wsz = (size_t)CYC * EMB * EMB * sizeof(unsigned short);
    const size_t psz = (size_t)BATCH * CYC * SEQ * EMB * sizeof(unsigned short);
    unsigned short* Wtq = (unsigned short*)(ws);
    unsigned short* Wtk = (unsigned short*)(ws + wsz);
    unsigned short* Wtv = (unsigned short*)(ws + 2 * wsz);
    unsigned short* Qp  = (unsigned short*)(ws + 3 * wsz);
    unsigned short* Kp  = (unsigned short*)(ws + 3 * wsz + psz);
    unsigned short* Vtp = (unsigned short*)(ws + 3 * wsz + 2 * psz);

    const dim3 tb(256);
    wt_kernel<<<dim3(4, 4, CYC), tb, 0, stream>>>(wq, Wtq);
    wt_kernel<<<dim3(4, 4, CYC), tb, 0, stream>>>(wk, Wtk);
    wt_kernel<<<dim3(4, 4, CYC), tb, 0, stream>>>(wv, Wtv);

    proj_kernel<<<dim3(BATCH * CYC, SEQ / 64, 3), tb, 0, stream>>>(
        query, key_, value, Wtq, Wtk, Wtv, bq, bk, bv, Qp, Kp, Vtp);

    attn_kernel<<<dim3(BATCH * CYC, SEQ / 64), tb, 0, stream>>>(Qp, Kp, Vtp, out);
}

// Round 4
// 333.429 us; speedup vs baseline: 1.0142x; 1.0142x over previous
//
#include <hip/hip_runtime.h>

// Problem constants (B,C,S,E) = (8,16,512,256), fp32 in/out.
constexpr int BATCH = 8;
constexpr int CYC   = 16;
constexpr int SEQ   = 512;
constexpr int EMB   = 256;

typedef __attribute__((ext_vector_type(8))) short bf16x8;
typedef __attribute__((ext_vector_type(4))) float f32x4;

__device__ __forceinline__ unsigned short f2bf(float x) {
    unsigned int u = __float_as_uint(x);
    u += 0x7fffu + ((u >> 16) & 1u);   // RNE
    return (unsigned short)(u >> 16);
}
__device__ __forceinline__ unsigned int pk2(float lo, float hi) {
    return (unsigned int)f2bf(lo) | ((unsigned int)f2bf(hi) << 16);
}
__device__ __forceinline__ f32x4 mfma16(bf16x8 a, bf16x8 b, f32x4 c) {
    return __builtin_amdgcn_mfma_f32_16x16x32_bf16(a, b, c, 0, 0, 0);
}
// async global->LDS, 16B/lane; LDS dst = wave-uniform base + lane*16
__device__ __forceinline__ void gll16(const void* g, void* l) {
    __builtin_amdgcn_global_load_lds(
        (const __attribute__((address_space(1))) void*)g,
        (__attribute__((address_space(3))) void*)l, 16, 0, 0);
}

// ---------------------------------------------------------------------------
// Kernel 0: W[c][e][f] fp32 -> Wt[c][f][e] bf16.  grid (4,4,C), block 256.
// EXACT R0 version.
// ---------------------------------------------------------------------------
__global__ __launch_bounds__(256) void wt_kernel(const float* __restrict__ W,
                                                 unsigned short* __restrict__ Wt) {
    __shared__ float tile[64][65];
    const int c  = blockIdx.z;
    const int e0 = blockIdx.x * 64;
    const int f0 = blockIdx.y * 64;
    const float* Wc = W + (size_t)c * EMB * EMB;
    unsigned short* Wtc = Wt + (size_t)c * EMB * EMB;
    const int t = threadIdx.x;
    {
        const int er = t >> 4;
        const int fc = (t & 15) * 4;
        for (int i = 0; i < 4; ++i) {
            const float4 v = *(const float4*)(Wc + (size_t)(e0 + er + i * 16) * EMB + f0 + fc);
            tile[er + i * 16][fc + 0] = v.x;
            tile[er + i * 16][fc + 1] = v.y;
            tile[er + i * 16][fc + 2] = v.z;
            tile[er + i * 16][fc + 3] = v.w;
        }
    }
    __syncthreads();
    {
        const int fr = t >> 4;
        const int ec = (t & 15) * 4;
        for (int i = 0; i < 4; ++i) {
            const int f = fr + i * 16;
            ushort4 o;
            o.x = f2bf(tile[ec + 0][f]);
            o.y = f2bf(tile[ec + 1][f]);
            o.z = f2bf(tile[ec + 2][f]);
            o.w = f2bf(tile[ec + 3][f]);
            *(ushort4*)(Wtc + (size_t)(f0 + f) * EMB + e0 + ec) = o;
        }
    }
}

// ---------------------------------------------------------------------------
// Kernel 1 (v4): merged q/k/v projection.  Y = relu(X_f32 @ W + bias) * scale.
// grid (128, 8, 3), block 256, LDS 40960 (4 blocks/CU).  BK=32, 8 K-steps.
// Changes vs v3 (sync-point halving — the ONLY kernel changed this round):
//   * ONE barrier per K-step (was 2).  bstage(k+1) moved AFTER the barrier:
//     buffer cur^1 is idle there (every wave's reads of it completed behind
//     its own lgkmcnt(0) before the previous barrier).
//   * A-regs double-buffered (+8 VGPR): aload(k+1) issued at step top.
//     Counted waits, never 0 mid-loop:
//       vmcnt(6): A(k) regs ready   [out: B(k)4 + A(k+1)2]
//       vmcnt(2): B(k) landed       [out: A(k+1)2]
//   * Epilogue: 8 __syncthreads -> 1.  Per-wave scratch + same-wave DS ops
//     are in-order; block barriers there were pure overhead.
//   * V path: per-wave LDS transpose + coalesced 16B row stores (was 8B
//     stores at 1KB stride = 64 lines/instr).
// ---------------------------------------------------------------------------
__global__ __launch_bounds__(256, 4) void proj_kernel(
    const float* __restrict__ Xq, const float* __restrict__ Xk,
    const float* __restrict__ Xv,
    const unsigned short* __restrict__ Wq, const unsigned short* __restrict__ Wk,
    const unsigned short* __restrict__ Wv,
    const float* __restrict__ Bq, const float* __restrict__ Bk,
    const float* __restrict__ Bv,
    unsigned short* __restrict__ Yq, unsigned short* __restrict__ Yk,
    unsigned short* __restrict__ Yv)
{
    __shared__ unsigned short smem[20480];            // 40,960 B
    // carve: As[b] = smem + b*2048      (64 x 32 bf16, 4 KiB each)
    //        Bs[b] = smem + 4096 + b*8192 (256 x 32 bf16, 16 KiB each)

    const int z = blockIdx.z;
    const float* X = z == 0 ? Xq : z == 1 ? Xk : Xv;
    const unsigned short* Wt = z == 0 ? Wq : z == 1 ? Wk : Wv;
    const float* bias = z == 0 ? Bq : z == 1 ? Bk : Bv;
    unsigned short* Y = z == 0 ? Yq : z == 1 ? Yk : Yv;
    const float scale = z == 0 ? 0.0625f : 1.0f;   // E^-0.5 folded into q

    const int bc = blockIdx.x;
    const int c  = bc & (CYC - 1);
    const int m0 = blockIdx.y * 64;
    const float* Xb = X + (size_t)bc * SEQ * EMB;
    const unsigned short* Wc = Wt + (size_t)c * EMB * EMB;
    const float* bb = bias + (size_t)c * EMB;
    unsigned short* Yb = Y + (size_t)bc * SEQ * EMB;

    const int tid  = threadIdx.x;
    const int lane = tid & 63, w = tid >> 6;
    const int ln   = lane & 15, quad = lane >> 4;
    const int wu   = __builtin_amdgcn_readfirstlane(w);

    // A reg-stage: thread t owns row ar = t>>2, 8 floats at col (t&3)*8.
    const int ar = tid >> 2, ac = (tid & 3) * 8;
    // B gll: per call 16 rows x 64B; source chunk ^ ((row-in-group)>>1 & 3).
    const int brow = lane >> 2;
    const int gch  = (lane & 3) ^ ((lane >> 3) & 3);
    const int bslot = quad ^ ((ln >> 1) & 3);  // B frag un-swizzle

    f32x4 acc[4][4];
    for (int i = 0; i < 4; ++i)
        for (int j = 0; j < 4; ++j) acc[i][j] = (f32x4){0.f, 0.f, 0.f, 0.f};

    const float* aptr = Xb + (size_t)(m0 + ar) * EMB + ac;
    float4 av[2][2];                           // double-buffered A in-flight regs

    auto aload = [&](int kk, float4* dst) {    // 2 global_load_dwordx4
        const float* p = aptr + kk * 32;
        dst[0] = *(const float4*)p;
        dst[1] = *(const float4*)(p + 4);
    };
    auto bstage = [&](int kk, int b) {         // 4 global_load_lds_dwordx4
        const int k0 = kk * 32;
        unsigned short* Bb = smem + 4096 + b * 8192;
#pragma unroll
        for (int j = 0; j < 4; ++j) {
            const int r0 = wu * 64 + j * 16;
            gll16(Wc + (size_t)(r0 + brow) * EMB + k0 + gch * 8,
                  Bb + (size_t)r0 * 32);
        }
    };

    aload(0, av[0]);
    __builtin_amdgcn_sched_barrier(0);
    bstage(0, 0);                              // out: A0(2) + B0(4) = 6

#pragma unroll
    for (int kk = 0; kk < 8; ++kk) {
        const int cur = kk & 1;
        unsigned short* As = smem + cur * 2048;
        unsigned short* Bs = smem + 4096 + cur * 8192;

        if (kk < 7) {
            aload(kk + 1, av[cur ^ 1]);        // out: B(k)4 + A(k+1)2 (+A(k)2)
            asm volatile("s_waitcnt vmcnt(6)" ::: "memory");   // A(k) ready
        } else {
            asm volatile("s_waitcnt vmcnt(4)" ::: "memory");   // A(7) ready
        }
        {   // pack fp32->bf16 once, one ds_write_b128 per thread
            int4 pk;
            pk.x = pk2(av[cur][0].x, av[cur][0].y);
            pk.y = pk2(av[cur][0].z, av[cur][0].w);
            pk.z = pk2(av[cur][1].x, av[cur][1].y);
            pk.w = pk2(av[cur][1].z, av[cur][1].w);
            *(int4*)&As[ar * 32 + ac] = pk;
        }
        if (kk < 7) {
            asm volatile("s_waitcnt vmcnt(2)" ::: "memory");   // B(k) landed
        } else {
            asm volatile("s_waitcnt vmcnt(0)" ::: "memory");
        }
        asm volatile("s_waitcnt lgkmcnt(0)" ::: "memory");     // A write visible
        __builtin_amdgcn_s_barrier();                          // ONE barrier/step
        __builtin_amdgcn_sched_barrier(0);
        if (kk < 7) bstage(kk + 1, cur ^ 1);   // buffer cur^1 idle past barrier

        bf16x8 af[4], bfv[4];
#pragma unroll
        for (int i = 0; i < 4; ++i)
            af[i] = *(const bf16x8*)&As[(i * 16 + ln) * 32 + quad * 8];
#pragma unroll
        for (int j = 0; j < 4; ++j)
            bfv[j] = *(const bf16x8*)&Bs[(w * 64 + j * 16 + ln) * 32 + bslot * 8];
#pragma unroll
        for (int i = 0; i < 4; ++i)
#pragma unroll
            for (int j = 0; j < 4; ++j)
                acc[i][j] = mfma16(af[i], bfv[j], acc[i][j]);

        __builtin_amdgcn_sched_barrier(0);
        asm volatile("s_waitcnt lgkmcnt(0)" ::: "memory");     // frag reads done
    }
    __syncthreads();   // K-loop LDS dead everywhere; epilogue scratch may reuse

    // Epilogue.  C/D layout: col = lane&15, row = quad*4 + reg  [m89-verified]
    float bvj[4];
#pragma unroll
    for (int j = 0; j < 4; ++j) bvj[j] = bb[w * 64 + j * 16 + ln];

    if (z != 2) {
        // per-wave LDS transpose tile [16][72] -> coalesced 16B row stores.
        // Per-wave private scratch + same-wave DS ordering => NO barriers.
        unsigned short* ep = smem + w * 1152;
        for (int i = 0; i < 4; ++i) {
            for (int j = 0; j < 4; ++j)
                for (int r = 0; r < 4; ++r)
                    ep[(quad * 4 + r) * 72 + j * 16 + ln] =
                        f2bf(fmaxf(acc[i][j][r] + bvj[j], 0.f) * scale);
            for (int h = 0; h < 2; ++h) {
                const int cid = lane + h * 64;       // [16 rows][8 chunks]
                const int row = cid >> 3, ch = cid & 7;
                *(bf16x8*)&Yb[(size_t)(m0 + i * 16 + row) * EMB + w * 64 + ch * 8] =
                    *(const bf16x8*)&ep[row * 72 + ch * 8];
            }
        }
    } else {
        // V path: per-wave transpose [64 f][76 pad m] -> coalesced 16B stores
        // of Yb[f][t] rows (was: ushort4 scatter at 1KB stride).
        unsigned short* ep = smem + w * 4864;        // 4 x 9728B = 38912 <= 40960
        for (int j = 0; j < 4; ++j) {
            const int fr = j * 16 + ln;
            for (int i = 0; i < 4; ++i) {
                ushort4 u;
                u.x = f2bf(fmaxf(acc[i][j][0] + bvj[j], 0.f) * scale);
                u.y = f2bf(fmaxf(acc[i][j][1] + bvj[j], 0.f) * scale);
                u.z = f2bf(fmaxf(acc[i][j][2] + bvj[j], 0.f) * scale);
                u.w = f2bf(fmaxf(acc[i][j][3] + bvj[j], 0.f) * scale);
                *(ushort4*)&ep[fr * 76 + i * 16 + quad * 4] = u;
            }
        }
        const int fg0 = w * 64;
        for (int h = 0; h < 8; ++h) {
            const int cid = lane + h * 64;           // [64 rows][8 chunks]
            const int row = cid >> 3, ch = cid & 7;
            *(bf16x8*)&Yb[(size_t)(fg0 + row) * SEQ + m0 + ch * 8] =
                *(const bf16x8*)&ep[row * 76 + ch * 8];
        }
    }
}

// ---------------------------------------------------------------------------
// Kernel 2: attention per (b,c) — EXACT R0 version (85 us, verified).
// ---------------------------------------------------------------------------
__global__ __launch_bounds__(256) void attn_kernel(
    const unsigned short* __restrict__ Qp, const unsigned short* __restrict__ Kp,
    const unsigned short* __restrict__ Vt, float* __restrict__ Out)
{
    __shared__ unsigned short Ks[32][264];  // [t][e]
    __shared__ unsigned short Vs[256][40];  // [e][t]
    __shared__ unsigned short Ps[64][40];   // [m][t]
    const int bc = blockIdx.x;
    const int qt = blockIdx.y;
    const unsigned short* Qb = Qp + (size_t)bc * SEQ * EMB;
    const unsigned short* Kb = Kp + (size_t)bc * SEQ * EMB;
    const unsigned short* Vb = Vt + (size_t)bc * SEQ * EMB;  // [e][t]
    float* Ob = Out + (size_t)bc * SEQ * EMB;

    const int tid  = threadIdx.x;
    const int lane = tid & 63, w = tid >> 6;
    const int ln   = lane & 15, quad = lane >> 4;

    bf16x8 qf[8];
    const int qrow = qt * 64 + w * 16 + ln;
    for (int ke = 0; ke < 8; ++ke)
        qf[ke] = *(const bf16x8*)(Qb + (size_t)qrow * EMB + ke * 32 + quad * 8);

    f32x4 of[16];
    for (int n = 0; n < 16; ++n) of[n] = (f32x4){0.f, 0.f, 0.f, 0.f};
    float lsum[4] = {0.f, 0.f, 0.f, 0.f};

    for (int tt = 0; tt < 16; ++tt) {
        const int t0 = tt * 32;
        for (int i = 0; i < 4; ++i) {       // stage K chunk: 32 x 256 bf16
            const int idx = tid + i * 256;
            const int r = idx >> 5, c8 = (idx & 31) * 8;
            *(bf16x8*)&Ks[r][c8] = *(const bf16x8*)(Kb + (size_t)(t0 + r) * EMB + c8);
        }
        for (int i = 0; i < 4; ++i) {       // stage V chunk: 256 x 32 bf16
            const int idx = tid + i * 256;
            const int e = idx >> 2, c8 = (idx & 3) * 8;
            *(bf16x8*)&Vs[e][c8] = *(const bf16x8*)(Vb + (size_t)e * SEQ + t0 + c8);
        }
        __syncthreads();

        // QK^T
        f32x4 sf0 = (f32x4){0.f,0.f,0.f,0.f}, sf1 = (f32x4){0.f,0.f,0.f,0.f};
        for (int ke = 0; ke < 8; ++ke) {
            bf16x8 b0 = *(const bf16x8*)&Ks[ln][ke * 32 + quad * 8];
            bf16x8 b1 = *(const bf16x8*)&Ks[16 + ln][ke * 32 + quad * 8];
            sf0 = mfma16(qf[ke], b0, sf0);
            sf1 = mfma16(qf[ke], b1, sf1);
        }

        float p0[4], p1[4];
        for (int r = 0; r < 4; ++r) {
            p0[r] = __expf(sf0[r]);
            p1[r] = __expf(sf1[r]);
            lsum[r] += p0[r] + p1[r];
        }
        for (int r = 0; r < 4; ++r) {
            Ps[w * 16 + quad * 4 + r][ln]      = f2bf(p0[r]);
            Ps[w * 16 + quad * 4 + r][16 + ln] = f2bf(p1[r]);
        }
        __syncthreads();

        // PV: O[m][e] += P[m][t] V[t][e]
        bf16x8 af = *(const bf16x8*)&Ps[w * 16 + ln][quad * 8];
        for (int n = 0; n < 16; ++n) {
            bf16x8 bv = *(const bf16x8*)&Vs[n * 16 + ln][quad * 8];
            of[n] = mfma16(af, bv, of[n]);
        }
        __syncthreads();
    }

    for (int off = 1; off < 16; off <<= 1)
        for (int r = 0; r < 4; ++r)
            lsum[r] += __shfl_xor(lsum[r], off, 64);
    float inv[4];
    for (int r = 0; r < 4; ++r) inv[r] = 1.0f / lsum[r];
    const int mbase = qt * 64 + w * 16 + quad * 4;
    for (int n = 0; n < 16; ++n)
        for (int r = 0; r < 4; ++r)
            Ob[(size_t)(mbase + r) * EMB + n * 16 + ln] = of[n][r] * inv[r];
}

// ---------------------------------------------------------------------------
extern "C" void kernel_launch(void* const* d_in, const int* in_sizes, int n_in,
                              void* d_out, int out_size, void* d_ws, size_t ws_size,
                              hipStream_t stream) {
    const float* query = (const float*)d_in[0];
    const float* key_  = (const float*)d_in[1];
    const float* value = (const float*)d_in[2];
    const float* wq = (const float*)d_in[3];
    const float* wk = (const float*)d_in[4];
    const float* wv = (const float*)d_in[5];
    const float* bq = (const float*)d_in[6];
    const float* bk = (const float*)d_in[7];
    const float* bv = (const float*)d_in[8];
    float* out = (float*)d_out;

    // Workspace: Wt q/k/v bf16 (2 MiB ea) | Qp, Kp, Vtp bf16 (32 MiB ea)
    char* ws = (char*)d_ws;
    const size_t wsz = (size_t)CYC * EMB * EMB * sizeof(unsigned short);
    const size_t psz = (size_t)BATCH * CYC * SEQ * EMB * sizeof(unsigned short);
    unsigned short* Wtq = (unsigned short*)(ws);
    unsigned short* Wtk = (unsigned short*)(ws + wsz);
    unsigned short* Wtv = (unsigned short*)(ws + 2 * wsz);
    unsigned short* Qp  = (unsigned short*)(ws + 3 * wsz);
    unsigned short* Kp  = (unsigned short*)(ws + 3 * wsz + psz);
    unsigned short* Vtp = (unsigned short*)(ws + 3 * wsz + 2 * psz);

    const dim3 tb(256);
    wt_kernel<<<dim3(4, 4, CYC), tb, 0, stream>>>(wq, Wtq);
    wt_kernel<<<dim3(4, 4, CYC), tb, 0, stream>>>(wk, Wtk);
    wt_kernel<<<dim3(4, 4, CYC), tb, 0, stream>>>(wv, Wtv);

    proj_kernel<<<dim3(BATCH * CYC, SEQ / 64, 3), tb, 0, stream>>>(
        query, key_, value, Wtq, Wtk, Wtv, bq, bk, bv, Qp, Kp, Vtp);

    attn_kernel<<<dim3(BATCH * CYC, SEQ / 64), tb, 0, stream>>>(Qp, Kp, Vtp, out);
}